// Round 14
// baseline (11543.696 us; speedup 1.0000x reference)
//
#include <hip/hip_runtime.h>

typedef unsigned short u16;
typedef unsigned int   u32;
typedef unsigned long long u64;
typedef long long      i64;
typedef __attribute__((ext_vector_type(8))) short  short8;
typedef __attribute__((ext_vector_type(8))) __bf16 bf16x8;
typedef __attribute__((ext_vector_type(4))) float  f32x4;

#define W_N   2048
#define C_N   24
#define E_N   512
#define H_N   1024
#define G3_N  3072
#define CH    256      // fallback phase-1 word chunk
#define SEG   512      // fallback phase-2 word segment
#define NBLK  64       // seq: blocks per direction
#define COLS  16       // seq: h columns per block (4 per wave)
#define SENT  0xFFFFFFFFu

#define MD_BF16 0u
#define MD_F32  1u
#define MD_ZERO 2u

__device__ inline float bf2f(u16 u) { union { u32 i; float f; } v; v.i = ((u32)u) << 16; return v.f; }
__device__ inline u16 f2bf(float f) {
  union { float f; u32 i; } v; v.f = f;
  u32 i = v.i;
  u32 r = (i + 0x7fffu + ((i >> 16) & 1u)) >> 16;
  return (u16)r;
}
__device__ inline float ld1(const void* p, size_t eoff, u32 md) {
  if (md == MD_F32) return ((const float*)p)[eoff];
  if (md == MD_ZERO) return 0.f;
  return bf2f(((const u16*)p)[eoff]);
}
__device__ inline short8 ld8(const void* p, size_t eoff, u32 md) {
  short8 r;
  if (md == MD_BF16) return *(const short8*)((const u16*)p + eoff);
  if (md == MD_ZERO) {
#pragma unroll
    for (int i = 0; i < 8; ++i) r[i] = 0;
    return r;
  }
  const float* f = (const float*)p + eoff;
#pragma unroll
  for (int i = 0; i < 8; ++i) r[i] = (short)f2bf(f[i]);
  return r;
}

// split fp32 -> bf16 hi + bf16 lo (hi = RN(f), lo = RN(f - hi))
__device__ inline void split8(f32x4 v0, f32x4 v1, bf16x8& hi, bf16x8& lo) {
#pragma unroll
  for (int i = 0; i < 4; ++i) {
    float f = v0[i];
    __bf16 h = (__bf16)f;
    hi[i] = h;
    lo[i] = (__bf16)(f - (float)h);
  }
#pragma unroll
  for (int i = 0; i < 4; ++i) {
    float f = v1[i];
    __bf16 h = (__bf16)f;
    hi[4 + i] = h;
    lo[4 + i] = (__bf16)(f - (float)h);
  }
}

__device__ inline void ldsplit(const void* p, size_t eoff, u32 md,
                               bf16x8& hi, bf16x8& lo) {
  if (md == MD_F32) {
    const float* f = (const float*)p + eoff;
    f32x4 v0 = *(const f32x4*)f;
    f32x4 v1 = *(const f32x4*)(f + 4);
    split8(v0, v1, hi, lo);
  } else if (md == MD_BF16) {
    union { short8 s; bf16x8 b; } u;
    u.s = *(const short8*)((const u16*)p + eoff);
    hi = u.b;
#pragma unroll
    for (int i = 0; i < 8; ++i) lo[i] = (__bf16)0.f;
  } else {
#pragma unroll
    for (int i = 0; i < 8; ++i) { hi[i] = (__bf16)0.f; lo[i] = (__bf16)0.f; }
  }
}

// ---- one merged sniff launch: block 0 = x dtype, blocks 1..13 = tensors ----
struct PtrPack { const void* p[14]; };

__global__ void sniffall_kernel(PtrPack pk, u32* __restrict__ flags) {
  if (threadIdx.x != 0) return;
  const int b = blockIdx.x;
  if (b == 0) {
    const int* xi = (const int*)pk.p[0];
    int oddzero = 0;
    for (int i = 0; i < 128; ++i)
      if (xi[2 * i + 1] == 0) oddzero++;
    flags[0] = (oddzero >= 120) ? 1u : 0u;   // 1 => int64
  } else {
    const u16* t = (const u16*)pk.p[b];
    int cnt = 0, nz = 0;
    for (int i = 0; i < 512; ++i) {
      u32 v = t[i];
      if (v != 0u) nz++;
      u32 e = (v >> 7) & 0xffu;
      if (e >= 100u && e <= 130u) cnt++;
    }
    flags[b] = (nz == 0) ? MD_ZERO : ((cnt >= 440) ? MD_BF16 : MD_F32);
  }
}

// ---- pre-split a weight tensor into bf16 hi/lo planes ----------------------
__global__ __launch_bounds__(256)
void wsplit_kernel(const void* __restrict__ W, u16* __restrict__ whi,
                   u16* __restrict__ wlo, const u32* __restrict__ flags,
                   int fi, int n8) {
  const int idx = blockIdx.x * 256 + threadIdx.x;
  if (idx >= n8) return;
  bf16x8 hi, lo;
  ldsplit(W, (size_t)idx * 8, flags[fi], hi, lo);
  *(bf16x8*)&whi[(size_t)idx * 8] = hi;
  *(bf16x8*)&wlo[(size_t)idx * 8] = lo;
}

// ---- split-bf16 MFMA GEMM ---------------------------------------------------
// GATHER=0: A rows = m_base+bm0+row. GATHER=1: rows via x-index gather.
// GATHER=2: rows clamped to [0,100] (emb-table precompute).
#define SWZ(row, kc) (((row) << 6) + ((kc) ^ (((row) & 7) << 3)))

template<int GATHER>
__global__ __launch_bounds__(256)
void mgemm_kernel(const void* __restrict__ A, const void* __restrict__ Wt,
                  const void* __restrict__ bias, float* __restrict__ Cout,
                  const void* __restrict__ X, int xoff, int gstride, int K,
                  const u32* __restrict__ flags, int afi, int wfi, int bfi,
                  int m_base) {
  __shared__ u16 AhS[64 * 64], AlS[64 * 64], BhS[64 * 64], BlS[64 * 64];
  __shared__ int arowS[64];
  const u32 am = (afi == -1) ? MD_BF16 : ((afi == -2) ? MD_F32 : flags[afi]);
  const u32 wm = flags[wfi];
  const u32 bm = flags[bfi];
  const int tid = threadIdx.x;
  const int bn0 = blockIdx.x * 64, bm0 = blockIdx.y * 64;
  if (GATHER) {
    if (tid < 64) {
      const int ar = m_base + bm0 + tid;
      int ix;
      if (GATHER == 2) ix = ar;
      else ix = flags[0] ? (int)((const i64*)X)[(size_t)ar * gstride + xoff]
                         : ((const int*)X)[(size_t)ar * gstride + xoff];
      arowS[tid] = min(max(ix, 0), 100);
    }
    __syncthreads();
  }
  const int wave = tid >> 6, lane = tid & 63;
  const int wr = (wave >> 1) * 32, wc = (wave & 1) * 32;
  const bool loA = (am == MD_F32), loB = (wm == MD_F32);

  f32x4 acc[2][2];
#pragma unroll
  for (int i = 0; i < 2; ++i)
#pragma unroll
    for (int j = 0; j < 2; ++j)
#pragma unroll
      for (int r = 0; r < 4; ++r) acc[i][j][r] = 0.f;

  for (int k0 = 0; k0 < K; k0 += 64) {
#pragma unroll
    for (int i = 0; i < 2; ++i) {
      const int ch = tid + i * 256;
      const int row = ch >> 3, kc = (ch & 7) * 8;
      {
        const int grow = GATHER ? arowS[row] : (m_base + bm0 + row);
        bf16x8 hi, lo;
        ldsplit(A, (size_t)grow * K + k0 + kc, am, hi, lo);
        const int o = SWZ(row, kc);
        *(bf16x8*)&AhS[o] = hi;
        *(bf16x8*)&AlS[o] = lo;
      }
      {
        bf16x8 hi, lo;
        ldsplit(Wt, (size_t)(bn0 + row) * K + k0 + kc, wm, hi, lo);
        const int o = SWZ(row, kc);
        *(bf16x8*)&BhS[o] = hi;
        *(bf16x8*)&BlS[o] = lo;
      }
    }
    __syncthreads();
#pragma unroll
    for (int ks = 0; ks < 64; ks += 32) {
      bf16x8 ah[2], al[2], bh[2], bl[2];
      const int lr = lane & 15, lk = ks + (lane >> 4) * 8;
#pragma unroll
      for (int i = 0; i < 2; ++i) {
        ah[i] = *(const bf16x8*)&AhS[SWZ(wr + i * 16 + lr, lk)];
        al[i] = *(const bf16x8*)&AlS[SWZ(wr + i * 16 + lr, lk)];
        bh[i] = *(const bf16x8*)&BhS[SWZ(wc + i * 16 + lr, lk)];
        bl[i] = *(const bf16x8*)&BlS[SWZ(wc + i * 16 + lr, lk)];
      }
#pragma unroll
      for (int i = 0; i < 2; ++i)
#pragma unroll
        for (int j = 0; j < 2; ++j) {
          acc[i][j] = __builtin_amdgcn_mfma_f32_16x16x32_bf16(ah[i], bh[j], acc[i][j], 0, 0, 0);
          if (loA)
            acc[i][j] = __builtin_amdgcn_mfma_f32_16x16x32_bf16(al[i], bh[j], acc[i][j], 0, 0, 0);
          if (loB)
            acc[i][j] = __builtin_amdgcn_mfma_f32_16x16x32_bf16(ah[i], bl[j], acc[i][j], 0, 0, 0);
        }
    }
    __syncthreads();
  }
  const int lr = lane & 15, m4 = (lane >> 4) * 4;
#pragma unroll
  for (int j = 0; j < 2; ++j) {
    const int n = bn0 + wc + j * 16 + lr;
    const float bv = ld1(bias, n, bm);
#pragma unroll
    for (int i = 0; i < 2; ++i) {
      const int m = bm0 + wr + i * 16 + m4;
#pragma unroll
      for (int r = 0; r < 4; ++r)
        Cout[(size_t)(m + r) * G3_N + n] = acc[i][j][r] + bv;
    }
  }
}

// ---- fused phase-1 char-GRU step (P-gather + pre-split pair staging) --------
__device__ inline void seg_pass_pair(
    const u16* __restrict__ Ahi, const u16* __restrict__ Alo, int bm0,
    const u16* __restrict__ Whi, const u16* __restrict__ Wlo, bool loB, int bn0,
    int tid, int wave, int lane,
    u16* AhS, u16* AlS, u16* B0h, u16* B0l, u16* B1h, u16* B1l, u16* B2h, u16* B2l,
    f32x4 (&aR)[2][2], f32x4 (&aZ)[2][2], f32x4 (&aN)[2][2]) {
  u16* BhS[3] = {B0h, B1h, B2h};
  u16* BlS[3] = {B0l, B1l, B2l};
  const int wr = (wave >> 1) * 32, wc = (wave & 1) * 32;
  const int K = H_N;
  for (int k0 = 0; k0 < K; k0 += 64) {
    __syncthreads();               // guard LDS reuse (prev k-step; also arowS)
#pragma unroll
    for (int i = 0; i < 2; ++i) {
      const int ch = tid + i * 256;
      const int row = ch >> 3, kc = (ch & 7) * 8;
      const int o = SWZ(row, kc);
      const size_t ao = (size_t)(bm0 + row) * K + k0 + kc;
      *(short8*)&AhS[o] = *(const short8*)&Ahi[ao];
      *(short8*)&AlS[o] = *(const short8*)&Alo[ao];
#pragma unroll
      for (int g = 0; g < 3; ++g) {
        const size_t wo = (size_t)(g * 1024 + bn0 + row) * K + k0 + kc;
        *(short8*)&BhS[g][o] = *(const short8*)&Whi[wo];
        *(short8*)&BlS[g][o] = *(const short8*)&Wlo[wo];
      }
    }
    __syncthreads();
#pragma unroll
    for (int ks = 0; ks < 64; ks += 32) {
      const int lr = lane & 15, lk = ks + (lane >> 4) * 8;
      bf16x8 ah[2], al[2];
#pragma unroll
      for (int i = 0; i < 2; ++i) {
        ah[i] = *(const bf16x8*)&AhS[SWZ(wr + i * 16 + lr, lk)];
        al[i] = *(const bf16x8*)&AlS[SWZ(wr + i * 16 + lr, lk)];
      }
#pragma unroll
      for (int g = 0; g < 3; ++g) {
        bf16x8 bh[2], bl[2];
#pragma unroll
        for (int j = 0; j < 2; ++j) {
          bh[j] = *(const bf16x8*)&BhS[g][SWZ(wc + j * 16 + lr, lk)];
          bl[j] = *(const bf16x8*)&BlS[g][SWZ(wc + j * 16 + lr, lk)];
        }
        f32x4 (&acc)[2][2] = (g == 0) ? aR : (g == 1) ? aZ : aN;
#pragma unroll
        for (int i = 0; i < 2; ++i)
#pragma unroll
          for (int j = 0; j < 2; ++j) {
            acc[i][j] = __builtin_amdgcn_mfma_f32_16x16x32_bf16(ah[i], bh[j], acc[i][j], 0, 0, 0);
            acc[i][j] = __builtin_amdgcn_mfma_f32_16x16x32_bf16(al[i], bh[j], acc[i][j], 0, 0, 0);
            if (loB)
              acc[i][j] = __builtin_amdgcn_mfma_f32_16x16x32_bf16(ah[i], bl[j], acc[i][j], 0, 0, 0);
          }
      }
    }
  }
}

__global__ __launch_bounds__(256)
void fgru_kernel(const float* __restrict__ P,
                 const u16* __restrict__ Whi, const u16* __restrict__ Wlo,
                 const void* __restrict__ bhh,
                 const float* __restrict__ hinF,
                 const u16* __restrict__ pInHi, const u16* __restrict__ pInLo,
                 float* __restrict__ houtF,
                 u16* __restrict__ pOutHi, u16* __restrict__ pOutLo,
                 float* __restrict__ wout,
                 const void* __restrict__ X, int xoff, int gstride,
                 const u32* __restrict__ flags) {
  __shared__ u16 AhS[64 * 64], AlS[64 * 64];
  __shared__ u16 B0h[64 * 64], B0l[64 * 64];
  __shared__ u16 B1h[64 * 64], B1l[64 * 64];
  __shared__ u16 B2h[64 * 64], B2l[64 * 64];
  __shared__ int arowS[64];
  const u32 wmH = flags[3], bmH = flags[5];
  const int tid = threadIdx.x, wave = tid >> 6, lane = tid & 63;
  const int bn0 = blockIdx.x * 64;   // h-column tile (0..1023)
  const int bm0 = blockIdx.y * 64;   // word-row tile (0..2047)
  if (tid < 64) {
    const int ar = bm0 + tid;
    int ix = flags[0] ? (int)((const i64*)X)[(size_t)ar * gstride + xoff]
                      : ((const int*)X)[(size_t)ar * gstride + xoff];
    arowS[tid] = min(max(ix, 0), 100);
  }
  // (seg_pass_pair begins with __syncthreads(), covering arowS for the epilogue)

  f32x4 aR[2][2], aZ[2][2], aHN[2][2];
#pragma unroll
  for (int i = 0; i < 2; ++i)
#pragma unroll
    for (int j = 0; j < 2; ++j)
#pragma unroll
      for (int r = 0; r < 4; ++r) {
        aR[i][j][r] = 0.f; aZ[i][j][r] = 0.f; aHN[i][j][r] = 0.f;
      }

  seg_pass_pair(pInHi, pInLo, bm0, Whi, Wlo, wmH == MD_F32, bn0,
                tid, wave, lane, AhS, AlS, B0h, B0l, B1h, B1l, B2h, B2l,
                aR, aZ, aHN);

  const int wr = (wave >> 1) * 32, wc = (wave & 1) * 32;
  const int lr = lane & 15, m4 = (lane >> 4) * 4;
#pragma unroll
  for (int j = 0; j < 2; ++j) {
    const int n = bn0 + wc + j * 16 + lr;
    const float bhR = ld1(bhh, n, bmH);
    const float bhZ = ld1(bhh, 1024 + n, bmH);
    const float bhN = ld1(bhh, 2048 + n, bmH);
#pragma unroll
    for (int i = 0; i < 2; ++i) {
      const int lm = wr + i * 16 + m4;
#pragma unroll
      for (int r4 = 0; r4 < 4; ++r4) {
        const size_t off = (size_t)(bm0 + lm + r4) * H_N + n;
        const float* Pr = P + (size_t)arowS[lm + r4] * G3_N + n;
        const float rg = 1.f / (1.f + expf(-(Pr[0]    + aR[i][j][r4] + bhR)));
        const float zg = 1.f / (1.f + expf(-(Pr[1024] + aZ[i][j][r4] + bhZ)));
        const float ng = tanhf(Pr[2048] + rg * (aHN[i][j][r4] + bhN));
        const float ho = (1.f - zg) * ng + zg * hinF[off];
        houtF[off] = ho;
        const __bf16 hb = (__bf16)ho;
        const __bf16 lb = (__bf16)(ho - (float)hb);
        union { __bf16 b; u16 u; } ch_, cl_;
        ch_.b = hb; cl_.b = lb;
        pOutHi[off] = ch_.u;
        pOutLo[off] = cl_.u;
        if (wout) wout[off] = ho;
      }
    }
  }
}

__global__ __launch_bounds__(256)
void gru_cell_kernel(const float* __restrict__ gi, const float* __restrict__ gh,
                     float* __restrict__ hf, float* __restrict__ wout, int mb) {
  const int idx = blockIdx.x * 256 + threadIdx.x;
  const int m = idx >> 10, j = idx & 1023;
  const float* gim = gi + (size_t)m * G3_N;
  const float* ghm = gh + (size_t)m * G3_N;
  const float ir = gim[j], iz = gim[1024 + j], inn = gim[2048 + j];
  const float hr = ghm[j], hz = ghm[1024 + j], hn = ghm[2048 + j];
  const float r = 1.f / (1.f + expf(-(ir + hr)));
  const float z = 1.f / (1.f + expf(-(iz + hz)));
  const float n = tanhf(inn + r * hn);
  const float ho = (1.f - z) * n + z * hf[idx];
  hf[idx] = ho;
  if (wout) wout[(size_t)(mb + m) * H_N + j] = ho;
}

// ============================================================================
// p2 mega-kernel: blocks 0..127 = word-GRU chains; blocks 128..3199 = the two
// gi GEMMs publishing into sentinel-prefilled G0/G1 via agent-scope atomic
// stores. Round 12 change: the chain's gi poll and h poll are MERGED into one
// combined loop (11 loads in flight, one detect) — removes a serialized IC
// round trip per step.
// ============================================================================
__device__ void mgemm_body(const float* __restrict__ A, const void* __restrict__ Wt,
                           const void* __restrict__ bias, float* __restrict__ Cout,
                           u32 wm, u32 bm, int bm0, int bn0, char* smem, int tid) {
  u16* AhS = (u16*)smem;
  u16* AlS = AhS + 4096;
  u16* BhS = AlS + 4096;
  u16* BlS = BhS + 4096;
  const int wave = tid >> 6, lane = tid & 63;
  const int wr = (wave >> 1) * 32, wc = (wave & 1) * 32;
  const bool loB = (wm == MD_F32);
  const int K = H_N;

  f32x4 acc[2][2];
#pragma unroll
  for (int i = 0; i < 2; ++i)
#pragma unroll
    for (int j = 0; j < 2; ++j)
#pragma unroll
      for (int r = 0; r < 4; ++r) acc[i][j][r] = 0.f;

  for (int k0 = 0; k0 < K; k0 += 64) {
#pragma unroll
    for (int i = 0; i < 2; ++i) {
      const int ch = tid + i * 256;
      const int row = ch >> 3, kc = (ch & 7) * 8;
      {
        bf16x8 hi, lo;
        ldsplit(A, (size_t)(bm0 + row) * K + k0 + kc, MD_F32, hi, lo);
        const int o = SWZ(row, kc);
        *(bf16x8*)&AhS[o] = hi;
        *(bf16x8*)&AlS[o] = lo;
      }
      {
        bf16x8 hi, lo;
        ldsplit(Wt, (size_t)(bn0 + row) * K + k0 + kc, wm, hi, lo);
        const int o = SWZ(row, kc);
        *(bf16x8*)&BhS[o] = hi;
        *(bf16x8*)&BlS[o] = lo;
      }
    }
    __syncthreads();
#pragma unroll
    for (int ks = 0; ks < 64; ks += 32) {
      bf16x8 ah[2], al[2], bh[2], bl[2];
      const int lr = lane & 15, lk = ks + (lane >> 4) * 8;
#pragma unroll
      for (int i = 0; i < 2; ++i) {
        ah[i] = *(const bf16x8*)&AhS[SWZ(wr + i * 16 + lr, lk)];
        al[i] = *(const bf16x8*)&AlS[SWZ(wr + i * 16 + lr, lk)];
        bh[i] = *(const bf16x8*)&BhS[SWZ(wc + i * 16 + lr, lk)];
        bl[i] = *(const bf16x8*)&BlS[SWZ(wc + i * 16 + lr, lk)];
      }
#pragma unroll
      for (int i = 0; i < 2; ++i)
#pragma unroll
        for (int j = 0; j < 2; ++j) {
          acc[i][j] = __builtin_amdgcn_mfma_f32_16x16x32_bf16(ah[i], bh[j], acc[i][j], 0, 0, 0);
          acc[i][j] = __builtin_amdgcn_mfma_f32_16x16x32_bf16(al[i], bh[j], acc[i][j], 0, 0, 0);
          if (loB)
            acc[i][j] = __builtin_amdgcn_mfma_f32_16x16x32_bf16(ah[i], bl[j], acc[i][j], 0, 0, 0);
        }
    }
    __syncthreads();
  }
  const int lr = lane & 15, m4 = (lane >> 4) * 4;
#pragma unroll
  for (int j = 0; j < 2; ++j) {
    const int n = bn0 + wc + j * 16 + lr;
    const float bv = ld1(bias, n, bm);
#pragma unroll
    for (int i = 0; i < 2; ++i) {
      const int m = bm0 + wr + i * 16 + m4;
#pragma unroll
      for (int r = 0; r < 4; ++r) {
        union { float f; u32 u; } cv; cv.f = acc[i][j][r] + bv;
        __hip_atomic_store((u32*)Cout + (size_t)(m + r) * G3_N + n, cv.u,
                           __ATOMIC_RELAXED, __HIP_MEMORY_SCOPE_AGENT);
      }
    }
  }
}

__device__ void seq_body(const void* __restrict__ Whh, const void* __restrict__ bhh,
                         const float* __restrict__ gi, float* __restrict__ ctx,
                         u32 wm, u32 bm, int dir, int blk, char* smem, int tid,
                         int nsteps) {
  u16* wsh = (u16*)smem;                   // 48*1024 bf16 = 96 KB
  const int dirofs = dir << 10;
  const int wave = tid >> 6, lane = tid & 63;
  const int j0 = blk * COLS;
  const int jw = wave * 4;

  for (int e = tid * 8; e < 48 * 1024; e += 256 * 8) {
    const int lr = e >> 10, col = e & 1023;
    const int g = lr >> 4, jj = lr & 15;
    *(short8*)&wsh[e] = ld8(Whh, (size_t)(g * 1024 + j0 + jj) * 1024 + col, wm);
  }
  float br = 0.f, bz = 0.f, bn = 0.f;
  if (lane < 4) {
    br = ld1(bhh, 0 * 1024 + j0 + jw + lane, bm);
    bz = ld1(bhh, 1 * 1024 + j0 + jw + lane, bm);
    bn = ld1(bhh, 2 * 1024 + j0 + jw + lane, bm);
  }
  __syncthreads();

  float hp = 0.f;
  for (int t = 0; t < nsteps; ++t) {
    const int row = dir ? (nsteps - 1 - t) : t;
    const u32* gp = (const u32*)(gi + (size_t)row * G3_N + (j0 + jw + (lane & 3)));
    u32 ga = 0, gb = 0, gc = 0;
    float hreg[16];
    if (t == 0) {
      // gi-only poll (no h dependency at t=0)
      for (;;) {
        if (lane < 4) {
          ga = __hip_atomic_load(gp,        __ATOMIC_RELAXED, __HIP_MEMORY_SCOPE_AGENT);
          gb = __hip_atomic_load(gp + 1024, __ATOMIC_RELAXED, __HIP_MEMORY_SCOPE_AGENT);
          gc = __hip_atomic_load(gp + 2048, __ATOMIC_RELAXED, __HIP_MEMORY_SCOPE_AGENT);
        }
        const bool bad = (lane < 4) && (ga == SENT || gb == SENT || gc == SENT);
        if (__ballot(bad) == 0ull) break;
      }
#pragma unroll
      for (int i = 0; i < 16; ++i) hreg[i] = 0.f;
    } else {
      // combined gi + h poll: 11 loads issued together, one detect per iter
      const int prow = dir ? (nsteps - t) : (t - 1);
      const u64* hsrc = (const u64*)(ctx + (size_t)prow * 2048 + dirofs);
      u64 hv[8];
      for (;;) {
        if (lane < 4) {
          ga = __hip_atomic_load(gp,        __ATOMIC_RELAXED, __HIP_MEMORY_SCOPE_AGENT);
          gb = __hip_atomic_load(gp + 1024, __ATOMIC_RELAXED, __HIP_MEMORY_SCOPE_AGENT);
          gc = __hip_atomic_load(gp + 2048, __ATOMIC_RELAXED, __HIP_MEMORY_SCOPE_AGENT);
        }
        bool bad = (lane < 4) && (ga == SENT || gb == SENT || gc == SENT);
#pragma unroll
        for (int c = 0; c < 8; ++c) {
          hv[c] = __hip_atomic_load(hsrc + c * 64 + lane,
                                    __ATOMIC_RELAXED, __HIP_MEMORY_SCOPE_AGENT);
          if ((u32)hv[c] == SENT || (u32)(hv[c] >> 32) == SENT)
            bad = true;
        }
        if (__ballot(bad) == 0ull) break;
      }
#pragma unroll
      for (int c = 0; c < 8; ++c) {
        union { u64 u; float f[2]; } cv; cv.u = hv[c];
        hreg[2 * c]     = cv.f[0];
        hreg[2 * c + 1] = cv.f[1];
      }
    }
    union { u32 u; float f; } c0, c1, c2;
    c0.u = ga; c1.u = gb; c2.u = gc;
    const float ir = c0.f, iz = c1.f, inn = c2.f;

    float sv[12];
#pragma unroll
    for (int g = 0; g < 3; ++g)
#pragma unroll
      for (int jj = 0; jj < 4; ++jj) {
        const u32* wrow = (const u32*)&wsh[(g * 16 + jw + jj) * 1024];
        float s = 0.f;
#pragma unroll
        for (int c = 0; c < 8; ++c) {
          const u32 u = wrow[c * 64 + lane];
          union { u32 i; float f; } lo2, hi2;
          lo2.i = u << 16; hi2.i = u & 0xffff0000u;
          s = fmaf(lo2.f, hreg[2 * c], s);
          s = fmaf(hi2.f, hreg[2 * c + 1], s);
        }
#pragma unroll
        for (int off = 32; off > 0; off >>= 1) s += __shfl_xor(s, off);
        sv[g * 4 + jj] = s;
      }
    if (lane < 4) {
      const float hr = (lane == 0 ? sv[0] : lane == 1 ? sv[1] : lane == 2 ? sv[2] : sv[3]) + br;
      const float hz = (lane == 0 ? sv[4] : lane == 1 ? sv[5] : lane == 2 ? sv[6] : sv[7]) + bz;
      const float hn = (lane == 0 ? sv[8] : lane == 1 ? sv[9] : lane == 2 ? sv[10] : sv[11]) + bn;
      const float r = 1.f / (1.f + expf(-(ir + hr)));
      const float z = 1.f / (1.f + expf(-(iz + hz)));
      const float n = tanhf(inn + r * hn);
      const float ho = (1.f - z) * n + z * hp;
      hp = ho;
      union { float f; u32 i; } v; v.f = ho;
      __hip_atomic_store((u32*)(ctx + (size_t)row * 2048) + dirofs + j0 + jw + lane,
                         v.i, __ATOMIC_RELAXED, __HIP_MEMORY_SCOPE_AGENT);
    }
  }
}

__global__ __launch_bounds__(256)
void p2_kernel(const void* __restrict__ Whf, const void* __restrict__ bhf,
               const void* __restrict__ Whb, const void* __restrict__ bhb,
               const void* __restrict__ Wif, const void* __restrict__ bif,
               const void* __restrict__ Wib, const void* __restrict__ bib,
               const float* __restrict__ wemb, float* __restrict__ G0,
               float* __restrict__ G1, float* __restrict__ ctx,
               const u32* __restrict__ flags, int nsteps) {
  __shared__ __align__(16) char smem[48 * 1024 * 2];   // 96 KB, carved per role
  const int tid = threadIdx.x;
  const int bid = blockIdx.x;
  if (bid < 2 * NBLK) {
    const int dir = bid >> 6, blk = bid & 63;
    seq_body(dir ? Whb : Whf, dir ? bhb : bhf, dir ? G1 : G0, ctx,
             flags[dir ? 11 : 7], flags[dir ? 13 : 9], dir, blk, smem, tid, nsteps);
  } else {
    int b = bid - 2 * NBLK;
    if (b < 1536) {                        // fwd gi: row tiles ascending
      const int bx = b % 48, by = b / 48;
      mgemm_body(wemb, Wif, bif, G0, flags[6], flags[8], by * 64, bx * 64, smem, tid);
    } else {                               // bwd gi: row tiles descending
      b -= 1536;
      const int bx = b % 48, by = 31 - (b / 48);
      mgemm_body(wemb, Wib, bib, G1, flags[10], flags[12], by * 64, bx * 64, smem, tid);
    }
  }
}

// Single-direction segment word-GRU (small-ws fallback, unchanged).
__global__ __launch_bounds__(256)
void seq_kernel(const void* __restrict__ Whh, const void* __restrict__ bhh,
                const float* __restrict__ gi, float* hb, unsigned* cnt,
                float* __restrict__ ctx, const u32* __restrict__ flags,
                int wfi, int bfi, int word_base, int rev, int dirofs) {
  const u32 wm = flags[wfi], bm = flags[bfi];
  const int blk = blockIdx.x;
  const int tid = threadIdx.x;
  const int wave = tid >> 6, lane = tid & 63;
  const int j0 = blk * 8;

  __shared__ __align__(16) u16 wsh[24 * 1024];
  __shared__ float hshf[1024];
  __shared__ float ghs[24];
  __shared__ float bhs[24];
  __shared__ float hnew[8];

  for (int e = tid * 8; e < 24 * 1024; e += 256 * 8) {
    const int lr = e >> 10, col = e & 1023;
    const int g = lr >> 3, jj = lr & 7;
    *(short8*)&wsh[e] = ld8(Whh, (size_t)(g * 1024 + j0 + jj) * 1024 + col, wm);
  }
  if (tid < 24) bhs[tid] = ld1(bhh, (tid >> 3) * 1024 + j0 + (tid & 7), bm);
  __syncthreads();

  unsigned target = 0;
  for (int t = 0; t < SEG; ++t) {
    const int row = rev ? (SEG - 1 - t) : t;
    const int wt = word_base + row;
    const u32* hsrc = (const u32*)(hb + (t & 1) * 1024);
    u32* hdst = (u32*)hshf;
    if (wave == 0) {
#pragma unroll
      for (int c = 0; c < 16; ++c)
        hdst[c * 64 + lane] = __hip_atomic_load(hsrc + c * 64 + lane,
                                                __ATOMIC_RELAXED, __HIP_MEMORY_SCOPE_AGENT);
    }
    __syncthreads();
    float hreg[16];
#pragma unroll
    for (int c = 0; c < 8; ++c) {
      const int kp = 2 * (c * 64 + lane);
      hreg[2 * c]     = hshf[kp];
      hreg[2 * c + 1] = hshf[kp + 1];
    }
#pragma unroll
    for (int q = 0; q < 6; ++q) {
      const int lr = wave * 6 + q;
      const u32* wrow = (const u32*)&wsh[lr * 1024];
      float s = 0.f;
#pragma unroll
      for (int c = 0; c < 8; ++c) {
        const u32 u = wrow[c * 64 + lane];
        union { u32 i; float f; } lo, hi;
        lo.i = u << 16; hi.i = u & 0xffff0000u;
        s = fmaf(lo.f, hreg[2 * c], s);
        s = fmaf(hi.f, hreg[2 * c + 1], s);
      }
#pragma unroll
      for (int off = 32; off > 0; off >>= 1) s += __shfl_xor(s, off);
      if (lane == 0) ghs[lr] = s;
    }
    __syncthreads();
    if (tid < 8) {
      const int jj = tid;
      const float hr = ghs[jj] + bhs[jj];
      const float hz = ghs[8 + jj] + bhs[8 + jj];
      const float hn = ghs[16 + jj] + bhs[16 + jj];
      const float* gim = gi + (size_t)row * G3_N + (j0 + jj);
      const float ir = gim[0], iz = gim[1024], inn = gim[2048];
      const float r = 1.f / (1.f + expf(-(ir + hr)));
      const float z = 1.f / (1.f + expf(-(iz + hz)));
      const float n = tanhf(inn + r * hn);
      const float hp = hshf[j0 + jj];
      const float ho = (1.f - z) * n + z * hp;
      ctx[(size_t)wt * 2048 + dirofs + j0 + jj] = ho;
      hnew[jj] = ho;
    }
    __syncthreads();
    if (tid < 8) {
      union { float f; u32 i; } v; v.f = hnew[tid];
      __hip_atomic_store((u32*)(hb + ((t + 1) & 1) * 1024) + blk * 8 + tid, v.i,
                         __ATOMIC_RELAXED, __HIP_MEMORY_SCOPE_AGENT);
    }
    target += 128;
    if (tid == 0) {
      __hip_atomic_fetch_add(cnt, 1u, __ATOMIC_RELEASE, __HIP_MEMORY_SCOPE_AGENT);
      while (__hip_atomic_load(cnt, __ATOMIC_ACQUIRE, __HIP_MEMORY_SCOPE_AGENT) < target)
        __builtin_amdgcn_s_sleep(2);
    }
    __syncthreads();
  }
}

extern "C" void kernel_launch(void* const* d_in, const int* in_sizes, int n_in,
                              void* d_out, int out_size, void* d_ws, size_t ws_size,
                              hipStream_t stream) {
  char* w = (char*)d_ws;
  // control block: flags [0,64) | cnts [64,1024) | hbuf fp32 [1024,17408)
  u32* flags = (u32*)(w);
  float* hbuf = (float*)(w + 1024);
  const size_t GBASE = 20480;

  hipMemsetAsync(w, 0, GBASE, stream);

  PtrPack pk;
  for (int i = 0; i < 14; ++i) pk.p[i] = d_in[i];
  sniffall_kernel<<<14, 64, 0, stream>>>(pk, flags);

  float* wemb = (float*)d_out;
  float* ctx  = (float*)d_out + (size_t)W_N * H_N;

  const size_t SZ_P  = (size_t)128 * G3_N * 4;         // 1.57 MB (P, 128 rows)
  const size_t SZ_G  = (size_t)W_N * G3_N * 4;         // 25.2 MB
  const size_t SZ_HF = (size_t)W_N * H_N * 4;          // 8.4 MB
  const size_t needA = GBASE + SZ_P + 2 * SZ_G + SZ_HF;

  if (ws_size >= needA) {
    // ---------- big-workspace path ----------
    float* P  = (float*)(w + GBASE);                   // emb @ Wih1^T + bih1
    float* G0 = (float*)(w + GBASE + SZ_P);            // gi fwd (phase 2)
    float* G1 = G0 + (size_t)W_N * G3_N;               // gi bwd (phase 2)
    float* HA = G1 + (size_t)W_N * G3_N;               // h fp32 double-buffer A
    float* HB = G0;                                    // h fp32 double-buffer B (G0 head)
    // phase-1 scratch overlaid in G0/G1 (both free until phase 2):
    u16* Whi  = (u16*)((char*)G0 + SZ_HF);             // pre-split Whh1 hi (6.3 MB)
    u16* Wlo  = Whi + (size_t)G3_N * H_N;              // pre-split Whh1 lo (6.3 MB)
    u16* pAhi = (u16*)G1;                              // h pair A hi (4.2 MB)
    u16* pAlo = pAhi + (size_t)W_N * H_N;              // h pair A lo
    u16* pBhi = pAlo + (size_t)W_N * H_N;              // h pair B hi
    u16* pBlo = pBhi + (size_t)W_N * H_N;              // h pair B lo

    hipMemsetAsync(HA, 0, SZ_HF, stream);              // h0 fp32 = 0
    hipMemsetAsync(pAhi, 0, (size_t)W_N * H_N * 4, stream);  // h0 pair = 0 (hi+lo)

    // prep: P[v] = emb[v] @ Wih1^T + bih1 (3-pass fp32) ; Whh1 -> hi/lo planes
    mgemm_kernel<2><<<dim3(G3_N / 64, 2), 256, 0, stream>>>(
        d_in[1], d_in[2], d_in[4], P, nullptr, 0, 0, E_N, flags, 1, 2, 4, 0);
    wsplit_kernel<<<(G3_N * H_N / 8 + 255) / 256, 256, 0, stream>>>(
        d_in[3], Whi, Wlo, flags, 3, G3_N * H_N / 8);

    // phase 1: 24 fused GRU-cell steps (pair-staged h-GEMM + P-gather + cell)
    float* hF[2]  = {HA, HB};
    u16*   pHi[2] = {pAhi, pBhi};
    u16*   pLo[2] = {pAlo, pBlo};
    dim3 gf(H_N / 64, W_N / 64);                       // 16 x 32
    for (int c = 0; c < C_N; ++c) {
      fgru_kernel<<<gf, 256, 0, stream>>>(P, Whi, Wlo, d_in[5],
                                          hF[c & 1], pHi[c & 1], pLo[c & 1],
                                          hF[(c + 1) & 1], pHi[(c + 1) & 1], pLo[(c + 1) & 1],
                                          (c == C_N - 1) ? wemb : (float*)nullptr,
                                          d_in[0], c, C_N, flags);
    }

    // sentinel prefill (G0/G1 were phase-1 scratch, so prefill AFTER phase 1)
    hipMemsetAsync(G0, 0xFF, SZ_G, stream);
    hipMemsetAsync(G1, 0xFF, SZ_G, stream);
    hipMemsetAsync(ctx, 0xFF, (size_t)W_N * 2048 * 4, stream);

    // phase 2 mega-kernel: seq chains + both gi GEMMs co-resident
    p2_kernel<<<2 * NBLK + 2 * 1536, 256, 0, stream>>>(
        d_in[7], d_in[9], d_in[11], d_in[13],
        d_in[6], d_in[8], d_in[10], d_in[12],
        wemb, G0, G1, ctx, flags, W_N);
  } else {
    // ---------- small-workspace fallback ----------
    float* G0  = (float*)(w + GBASE);
    float* GIc = G0;
    float* GHc = G0 + (size_t)CH * G3_N;
    float* HF  = (float*)(w + GBASE + (size_t)SEG * G3_N * 4);

    dim3 g1(G3_N / 64, CH / 64);
    for (int chk = 0; chk < W_N / CH; ++chk) {
      const int mb = chk * CH;
      hipMemsetAsync(HF, 0, (size_t)CH * H_N * 4, stream);
      for (int c = 0; c < C_N; ++c) {
        mgemm_kernel<1><<<g1, 256, 0, stream>>>(d_in[1], d_in[2], d_in[4], GIc,
                                                d_in[0], c, C_N, E_N, flags, 1, 2, 4, mb);
        mgemm_kernel<0><<<g1, 256, 0, stream>>>(HF, d_in[3], d_in[5], GHc,
                                                nullptr, 0, 0, H_N, flags, -2, 3, 5, 0);
        gru_cell_kernel<<<(CH * H_N) / 256, 256, 0, stream>>>(
            GIc, GHc, HF, (c == C_N - 1) ? wemb : (float*)nullptr, mb);
      }
    }
    dim3 g2(G3_N / 64, SEG / 64);
    for (int s = 0; s < W_N / SEG; ++s) {
      mgemm_kernel<0><<<g2, 256, 0, stream>>>(wemb, d_in[6], d_in[8], G0,
                                              nullptr, 0, 0, H_N, flags, -2, 6, 8, s * SEG);
      seq_kernel<<<128, 256, 0, stream>>>(d_in[7], d_in[9], G0, hbuf,
                                          (unsigned*)(w + 64 + (0 * 4 + s) * 64),
                                          ctx, flags, 7, 9, s * SEG, 0, 0);
    }
    for (int s = W_N / SEG - 1; s >= 0; --s) {
      mgemm_kernel<0><<<g2, 256, 0, stream>>>(wemb, d_in[10], d_in[12], G0,
                                              nullptr, 0, 0, H_N, flags, -2, 10, 12, s * SEG);
      seq_kernel<<<128, 256, 0, stream>>>(d_in[11], d_in[13], G0, hbuf + 2048,
                                          (unsigned*)(w + 64 + (1 * 4 + s) * 64),
                                          ctx, flags, 11, 13, s * SEG, 1, 1024);
    }
  }
}

// Round 15
// 8636.201 us; speedup vs baseline: 1.3367x; 1.3367x over previous
//
#include <hip/hip_runtime.h>

typedef unsigned short u16;
typedef unsigned int   u32;
typedef unsigned long long u64;
typedef long long      i64;
typedef __attribute__((ext_vector_type(8))) short  short8;
typedef __attribute__((ext_vector_type(8))) __bf16 bf16x8;
typedef __attribute__((ext_vector_type(4))) float  f32x4;

#define W_N   2048
#define C_N   24
#define E_N   512
#define H_N   1024
#define G3_N  3072
#define CH    256      // fallback phase-1 word chunk
#define SEG   512      // fallback phase-2 word segment
#define NBLK  64       // seq: blocks per direction
#define COLS  16       // seq: h columns per block (4 per wave)
#define SENT  0xFFFFFFFFu

#define MD_BF16 0u
#define MD_F32  1u
#define MD_ZERO 2u

__device__ inline float bf2f(u16 u) { union { u32 i; float f; } v; v.i = ((u32)u) << 16; return v.f; }
__device__ inline u16 f2bf(float f) {
  union { float f; u32 i; } v; v.f = f;
  u32 i = v.i;
  u32 r = (i + 0x7fffu + ((i >> 16) & 1u)) >> 16;
  return (u16)r;
}
__device__ inline float ld1(const void* p, size_t eoff, u32 md) {
  if (md == MD_F32) return ((const float*)p)[eoff];
  if (md == MD_ZERO) return 0.f;
  return bf2f(((const u16*)p)[eoff]);
}
__device__ inline short8 ld8(const void* p, size_t eoff, u32 md) {
  short8 r;
  if (md == MD_BF16) return *(const short8*)((const u16*)p + eoff);
  if (md == MD_ZERO) {
#pragma unroll
    for (int i = 0; i < 8; ++i) r[i] = 0;
    return r;
  }
  const float* f = (const float*)p + eoff;
#pragma unroll
  for (int i = 0; i < 8; ++i) r[i] = (short)f2bf(f[i]);
  return r;
}

// split fp32 -> bf16 hi + bf16 lo (hi = RN(f), lo = RN(f - hi))
__device__ inline void split8(f32x4 v0, f32x4 v1, bf16x8& hi, bf16x8& lo) {
#pragma unroll
  for (int i = 0; i < 4; ++i) {
    float f = v0[i];
    __bf16 h = (__bf16)f;
    hi[i] = h;
    lo[i] = (__bf16)(f - (float)h);
  }
#pragma unroll
  for (int i = 0; i < 4; ++i) {
    float f = v1[i];
    __bf16 h = (__bf16)f;
    hi[4 + i] = h;
    lo[4 + i] = (__bf16)(f - (float)h);
  }
}

__device__ inline void ldsplit(const void* p, size_t eoff, u32 md,
                               bf16x8& hi, bf16x8& lo) {
  if (md == MD_F32) {
    const float* f = (const float*)p + eoff;
    f32x4 v0 = *(const f32x4*)f;
    f32x4 v1 = *(const f32x4*)(f + 4);
    split8(v0, v1, hi, lo);
  } else if (md == MD_BF16) {
    union { short8 s; bf16x8 b; } u;
    u.s = *(const short8*)((const u16*)p + eoff);
    hi = u.b;
#pragma unroll
    for (int i = 0; i < 8; ++i) lo[i] = (__bf16)0.f;
  } else {
#pragma unroll
    for (int i = 0; i < 8; ++i) { hi[i] = (__bf16)0.f; lo[i] = (__bf16)0.f; }
  }
}

// ---- one merged sniff launch: block 0 = x dtype, blocks 1..13 = tensors ----
struct PtrPack { const void* p[14]; };

__global__ void sniffall_kernel(PtrPack pk, u32* __restrict__ flags) {
  if (threadIdx.x != 0) return;
  const int b = blockIdx.x;
  if (b == 0) {
    const int* xi = (const int*)pk.p[0];
    int oddzero = 0;
    for (int i = 0; i < 128; ++i)
      if (xi[2 * i + 1] == 0) oddzero++;
    flags[0] = (oddzero >= 120) ? 1u : 0u;   // 1 => int64
  } else {
    const u16* t = (const u16*)pk.p[b];
    int cnt = 0, nz = 0;
    for (int i = 0; i < 512; ++i) {
      u32 v = t[i];
      if (v != 0u) nz++;
      u32 e = (v >> 7) & 0xffu;
      if (e >= 100u && e <= 130u) cnt++;
    }
    flags[b] = (nz == 0) ? MD_ZERO : ((cnt >= 440) ? MD_BF16 : MD_F32);
  }
}

// ---- pre-split a weight tensor into bf16 hi/lo planes ----------------------
__global__ __launch_bounds__(256)
void wsplit_kernel(const void* __restrict__ W, u16* __restrict__ whi,
                   u16* __restrict__ wlo, const u32* __restrict__ flags,
                   int fi, int n8) {
  const int idx = blockIdx.x * 256 + threadIdx.x;
  if (idx >= n8) return;
  bf16x8 hi, lo;
  ldsplit(W, (size_t)idx * 8, flags[fi], hi, lo);
  *(bf16x8*)&whi[(size_t)idx * 8] = hi;
  *(bf16x8*)&wlo[(size_t)idx * 8] = lo;
}

// ---- split-bf16 MFMA GEMM ---------------------------------------------------
// GATHER=0: A rows = m_base+bm0+row. GATHER=1: rows via x-index gather.
// GATHER=2: rows clamped to [0,100] (emb-table precompute).
#define SWZ(row, kc) (((row) << 6) + ((kc) ^ (((row) & 7) << 3)))

template<int GATHER>
__global__ __launch_bounds__(256)
void mgemm_kernel(const void* __restrict__ A, const void* __restrict__ Wt,
                  const void* __restrict__ bias, float* __restrict__ Cout,
                  const void* __restrict__ X, int xoff, int gstride, int K,
                  const u32* __restrict__ flags, int afi, int wfi, int bfi,
                  int m_base) {
  __shared__ u16 AhS[64 * 64], AlS[64 * 64], BhS[64 * 64], BlS[64 * 64];
  __shared__ int arowS[64];
  const u32 am = (afi == -1) ? MD_BF16 : ((afi == -2) ? MD_F32 : flags[afi]);
  const u32 wm = flags[wfi];
  const u32 bm = flags[bfi];
  const int tid = threadIdx.x;
  const int bn0 = blockIdx.x * 64, bm0 = blockIdx.y * 64;
  if (GATHER) {
    if (tid < 64) {
      const int ar = m_base + bm0 + tid;
      int ix;
      if (GATHER == 2) ix = ar;
      else ix = flags[0] ? (int)((const i64*)X)[(size_t)ar * gstride + xoff]
                         : ((const int*)X)[(size_t)ar * gstride + xoff];
      arowS[tid] = min(max(ix, 0), 100);
    }
    __syncthreads();
  }
  const int wave = tid >> 6, lane = tid & 63;
  const int wr = (wave >> 1) * 32, wc = (wave & 1) * 32;
  const bool loA = (am == MD_F32), loB = (wm == MD_F32);

  f32x4 acc[2][2];
#pragma unroll
  for (int i = 0; i < 2; ++i)
#pragma unroll
    for (int j = 0; j < 2; ++j)
#pragma unroll
      for (int r = 0; r < 4; ++r) acc[i][j][r] = 0.f;

  for (int k0 = 0; k0 < K; k0 += 64) {
#pragma unroll
    for (int i = 0; i < 2; ++i) {
      const int ch = tid + i * 256;
      const int row = ch >> 3, kc = (ch & 7) * 8;
      {
        const int grow = GATHER ? arowS[row] : (m_base + bm0 + row);
        bf16x8 hi, lo;
        ldsplit(A, (size_t)grow * K + k0 + kc, am, hi, lo);
        const int o = SWZ(row, kc);
        *(bf16x8*)&AhS[o] = hi;
        *(bf16x8*)&AlS[o] = lo;
      }
      {
        bf16x8 hi, lo;
        ldsplit(Wt, (size_t)(bn0 + row) * K + k0 + kc, wm, hi, lo);
        const int o = SWZ(row, kc);
        *(bf16x8*)&BhS[o] = hi;
        *(bf16x8*)&BlS[o] = lo;
      }
    }
    __syncthreads();
#pragma unroll
    for (int ks = 0; ks < 64; ks += 32) {
      bf16x8 ah[2], al[2], bh[2], bl[2];
      const int lr = lane & 15, lk = ks + (lane >> 4) * 8;
#pragma unroll
      for (int i = 0; i < 2; ++i) {
        ah[i] = *(const bf16x8*)&AhS[SWZ(wr + i * 16 + lr, lk)];
        al[i] = *(const bf16x8*)&AlS[SWZ(wr + i * 16 + lr, lk)];
        bh[i] = *(const bf16x8*)&BhS[SWZ(wc + i * 16 + lr, lk)];
        bl[i] = *(const bf16x8*)&BlS[SWZ(wc + i * 16 + lr, lk)];
      }
#pragma unroll
      for (int i = 0; i < 2; ++i)
#pragma unroll
        for (int j = 0; j < 2; ++j) {
          acc[i][j] = __builtin_amdgcn_mfma_f32_16x16x32_bf16(ah[i], bh[j], acc[i][j], 0, 0, 0);
          if (loA)
            acc[i][j] = __builtin_amdgcn_mfma_f32_16x16x32_bf16(al[i], bh[j], acc[i][j], 0, 0, 0);
          if (loB)
            acc[i][j] = __builtin_amdgcn_mfma_f32_16x16x32_bf16(ah[i], bl[j], acc[i][j], 0, 0, 0);
        }
    }
    __syncthreads();
  }
  const int lr = lane & 15, m4 = (lane >> 4) * 4;
#pragma unroll
  for (int j = 0; j < 2; ++j) {
    const int n = bn0 + wc + j * 16 + lr;
    const float bv = ld1(bias, n, bm);
#pragma unroll
    for (int i = 0; i < 2; ++i) {
      const int m = bm0 + wr + i * 16 + m4;
#pragma unroll
      for (int r = 0; r < 4; ++r)
        Cout[(size_t)(m + r) * G3_N + n] = acc[i][j][r] + bv;
    }
  }
}

// ---- fused phase-1 char-GRU step (P-gather + pre-split pair staging) --------
__device__ inline void seg_pass_pair(
    const u16* __restrict__ Ahi, const u16* __restrict__ Alo, int bm0,
    const u16* __restrict__ Whi, const u16* __restrict__ Wlo, bool loB, int bn0,
    int tid, int wave, int lane,
    u16* AhS, u16* AlS, u16* B0h, u16* B0l, u16* B1h, u16* B1l, u16* B2h, u16* B2l,
    f32x4 (&aR)[2][2], f32x4 (&aZ)[2][2], f32x4 (&aN)[2][2]) {
  u16* BhS[3] = {B0h, B1h, B2h};
  u16* BlS[3] = {B0l, B1l, B2l};
  const int wr = (wave >> 1) * 32, wc = (wave & 1) * 32;
  const int K = H_N;
  for (int k0 = 0; k0 < K; k0 += 64) {
    __syncthreads();               // guard LDS reuse (prev k-step; also arowS)
#pragma unroll
    for (int i = 0; i < 2; ++i) {
      const int ch = tid + i * 256;
      const int row = ch >> 3, kc = (ch & 7) * 8;
      const int o = SWZ(row, kc);
      const size_t ao = (size_t)(bm0 + row) * K + k0 + kc;
      *(short8*)&AhS[o] = *(const short8*)&Ahi[ao];
      *(short8*)&AlS[o] = *(const short8*)&Alo[ao];
#pragma unroll
      for (int g = 0; g < 3; ++g) {
        const size_t wo = (size_t)(g * 1024 + bn0 + row) * K + k0 + kc;
        *(short8*)&BhS[g][o] = *(const short8*)&Whi[wo];
        *(short8*)&BlS[g][o] = *(const short8*)&Wlo[wo];
      }
    }
    __syncthreads();
#pragma unroll
    for (int ks = 0; ks < 64; ks += 32) {
      const int lr = lane & 15, lk = ks + (lane >> 4) * 8;
      bf16x8 ah[2], al[2];
#pragma unroll
      for (int i = 0; i < 2; ++i) {
        ah[i] = *(const bf16x8*)&AhS[SWZ(wr + i * 16 + lr, lk)];
        al[i] = *(const bf16x8*)&AlS[SWZ(wr + i * 16 + lr, lk)];
      }
#pragma unroll
      for (int g = 0; g < 3; ++g) {
        bf16x8 bh[2], bl[2];
#pragma unroll
        for (int j = 0; j < 2; ++j) {
          bh[j] = *(const bf16x8*)&BhS[g][SWZ(wc + j * 16 + lr, lk)];
          bl[j] = *(const bf16x8*)&BlS[g][SWZ(wc + j * 16 + lr, lk)];
        }
        f32x4 (&acc)[2][2] = (g == 0) ? aR : (g == 1) ? aZ : aN;
#pragma unroll
        for (int i = 0; i < 2; ++i)
#pragma unroll
          for (int j = 0; j < 2; ++j) {
            acc[i][j] = __builtin_amdgcn_mfma_f32_16x16x32_bf16(ah[i], bh[j], acc[i][j], 0, 0, 0);
            acc[i][j] = __builtin_amdgcn_mfma_f32_16x16x32_bf16(al[i], bh[j], acc[i][j], 0, 0, 0);
            if (loB)
              acc[i][j] = __builtin_amdgcn_mfma_f32_16x16x32_bf16(ah[i], bl[j], acc[i][j], 0, 0, 0);
          }
      }
    }
  }
}

__global__ __launch_bounds__(256)
void fgru_kernel(const float* __restrict__ P,
                 const u16* __restrict__ Whi, const u16* __restrict__ Wlo,
                 const void* __restrict__ bhh,
                 const float* __restrict__ hinF,
                 const u16* __restrict__ pInHi, const u16* __restrict__ pInLo,
                 float* __restrict__ houtF,
                 u16* __restrict__ pOutHi, u16* __restrict__ pOutLo,
                 float* __restrict__ wout,
                 const void* __restrict__ X, int xoff, int gstride,
                 const u32* __restrict__ flags) {
  __shared__ u16 AhS[64 * 64], AlS[64 * 64];
  __shared__ u16 B0h[64 * 64], B0l[64 * 64];
  __shared__ u16 B1h[64 * 64], B1l[64 * 64];
  __shared__ u16 B2h[64 * 64], B2l[64 * 64];
  __shared__ int arowS[64];
  const u32 wmH = flags[3], bmH = flags[5];
  const int tid = threadIdx.x, wave = tid >> 6, lane = tid & 63;
  const int bn0 = blockIdx.x * 64;   // h-column tile (0..1023)
  const int bm0 = blockIdx.y * 64;   // word-row tile (0..2047)
  if (tid < 64) {
    const int ar = bm0 + tid;
    int ix = flags[0] ? (int)((const i64*)X)[(size_t)ar * gstride + xoff]
                      : ((const int*)X)[(size_t)ar * gstride + xoff];
    arowS[tid] = min(max(ix, 0), 100);
  }
  // (seg_pass_pair begins with __syncthreads(), covering arowS for the epilogue)

  f32x4 aR[2][2], aZ[2][2], aHN[2][2];
#pragma unroll
  for (int i = 0; i < 2; ++i)
#pragma unroll
    for (int j = 0; j < 2; ++j)
#pragma unroll
      for (int r = 0; r < 4; ++r) {
        aR[i][j][r] = 0.f; aZ[i][j][r] = 0.f; aHN[i][j][r] = 0.f;
      }

  seg_pass_pair(pInHi, pInLo, bm0, Whi, Wlo, wmH == MD_F32, bn0,
                tid, wave, lane, AhS, AlS, B0h, B0l, B1h, B1l, B2h, B2l,
                aR, aZ, aHN);

  const int wr = (wave >> 1) * 32, wc = (wave & 1) * 32;
  const int lr = lane & 15, m4 = (lane >> 4) * 4;
#pragma unroll
  for (int j = 0; j < 2; ++j) {
    const int n = bn0 + wc + j * 16 + lr;
    const float bhR = ld1(bhh, n, bmH);
    const float bhZ = ld1(bhh, 1024 + n, bmH);
    const float bhN = ld1(bhh, 2048 + n, bmH);
#pragma unroll
    for (int i = 0; i < 2; ++i) {
      const int lm = wr + i * 16 + m4;
#pragma unroll
      for (int r4 = 0; r4 < 4; ++r4) {
        const size_t off = (size_t)(bm0 + lm + r4) * H_N + n;
        const float* Pr = P + (size_t)arowS[lm + r4] * G3_N + n;
        const float rg = 1.f / (1.f + expf(-(Pr[0]    + aR[i][j][r4] + bhR)));
        const float zg = 1.f / (1.f + expf(-(Pr[1024] + aZ[i][j][r4] + bhZ)));
        const float ng = tanhf(Pr[2048] + rg * (aHN[i][j][r4] + bhN));
        const float ho = (1.f - zg) * ng + zg * hinF[off];
        houtF[off] = ho;
        const __bf16 hb = (__bf16)ho;
        const __bf16 lb = (__bf16)(ho - (float)hb);
        union { __bf16 b; u16 u; } ch_, cl_;
        ch_.b = hb; cl_.b = lb;
        pOutHi[off] = ch_.u;
        pOutLo[off] = cl_.u;
        if (wout) wout[off] = ho;
      }
    }
  }
}

__global__ __launch_bounds__(256)
void gru_cell_kernel(const float* __restrict__ gi, const float* __restrict__ gh,
                     float* __restrict__ hf, float* __restrict__ wout, int mb) {
  const int idx = blockIdx.x * 256 + threadIdx.x;
  const int m = idx >> 10, j = idx & 1023;
  const float* gim = gi + (size_t)m * G3_N;
  const float* ghm = gh + (size_t)m * G3_N;
  const float ir = gim[j], iz = gim[1024 + j], inn = gim[2048 + j];
  const float hr = ghm[j], hz = ghm[1024 + j], hn = ghm[2048 + j];
  const float r = 1.f / (1.f + expf(-(ir + hr)));
  const float z = 1.f / (1.f + expf(-(iz + hz)));
  const float n = tanhf(inn + r * hn);
  const float ho = (1.f - z) * n + z * hf[idx];
  hf[idx] = ho;
  if (wout) wout[(size_t)(mb + m) * H_N + j] = ho;
}

// ============================================================================
// p2 mega-kernel (REVERTED to round-11 form — best measured: 7.09 ms):
// blocks 0..127 = word-GRU chains (separate gi poll, then h poll); blocks
// 128..3199 = the two gi GEMMs publishing into sentinel-prefilled G0/G1 via
// agent-scope atomic stores. Round-14 lesson: folding the gi loads into the
// h-detect loop lengthens each detect iteration (11-load vmcnt drain) and
// doubles IC fetch — per-step 3.46 -> 4.93 µs. Detect-loop iteration time IS
// the binding resource; keep the h poll minimal.
// ============================================================================
__device__ void mgemm_body(const float* __restrict__ A, const void* __restrict__ Wt,
                           const void* __restrict__ bias, float* __restrict__ Cout,
                           u32 wm, u32 bm, int bm0, int bn0, char* smem, int tid) {
  u16* AhS = (u16*)smem;
  u16* AlS = AhS + 4096;
  u16* BhS = AlS + 4096;
  u16* BlS = BhS + 4096;
  const int wave = tid >> 6, lane = tid & 63;
  const int wr = (wave >> 1) * 32, wc = (wave & 1) * 32;
  const bool loB = (wm == MD_F32);
  const int K = H_N;

  f32x4 acc[2][2];
#pragma unroll
  for (int i = 0; i < 2; ++i)
#pragma unroll
    for (int j = 0; j < 2; ++j)
#pragma unroll
      for (int r = 0; r < 4; ++r) acc[i][j][r] = 0.f;

  for (int k0 = 0; k0 < K; k0 += 64) {
#pragma unroll
    for (int i = 0; i < 2; ++i) {
      const int ch = tid + i * 256;
      const int row = ch >> 3, kc = (ch & 7) * 8;
      {
        bf16x8 hi, lo;
        ldsplit(A, (size_t)(bm0 + row) * K + k0 + kc, MD_F32, hi, lo);
        const int o = SWZ(row, kc);
        *(bf16x8*)&AhS[o] = hi;
        *(bf16x8*)&AlS[o] = lo;
      }
      {
        bf16x8 hi, lo;
        ldsplit(Wt, (size_t)(bn0 + row) * K + k0 + kc, wm, hi, lo);
        const int o = SWZ(row, kc);
        *(bf16x8*)&BhS[o] = hi;
        *(bf16x8*)&BlS[o] = lo;
      }
    }
    __syncthreads();
#pragma unroll
    for (int ks = 0; ks < 64; ks += 32) {
      bf16x8 ah[2], al[2], bh[2], bl[2];
      const int lr = lane & 15, lk = ks + (lane >> 4) * 8;
#pragma unroll
      for (int i = 0; i < 2; ++i) {
        ah[i] = *(const bf16x8*)&AhS[SWZ(wr + i * 16 + lr, lk)];
        al[i] = *(const bf16x8*)&AlS[SWZ(wr + i * 16 + lr, lk)];
        bh[i] = *(const bf16x8*)&BhS[SWZ(wc + i * 16 + lr, lk)];
        bl[i] = *(const bf16x8*)&BlS[SWZ(wc + i * 16 + lr, lk)];
      }
#pragma unroll
      for (int i = 0; i < 2; ++i)
#pragma unroll
        for (int j = 0; j < 2; ++j) {
          acc[i][j] = __builtin_amdgcn_mfma_f32_16x16x32_bf16(ah[i], bh[j], acc[i][j], 0, 0, 0);
          acc[i][j] = __builtin_amdgcn_mfma_f32_16x16x32_bf16(al[i], bh[j], acc[i][j], 0, 0, 0);
          if (loB)
            acc[i][j] = __builtin_amdgcn_mfma_f32_16x16x32_bf16(ah[i], bl[j], acc[i][j], 0, 0, 0);
        }
    }
    __syncthreads();
  }
  const int lr = lane & 15, m4 = (lane >> 4) * 4;
#pragma unroll
  for (int j = 0; j < 2; ++j) {
    const int n = bn0 + wc + j * 16 + lr;
    const float bv = ld1(bias, n, bm);
#pragma unroll
    for (int i = 0; i < 2; ++i) {
      const int m = bm0 + wr + i * 16 + m4;
#pragma unroll
      for (int r = 0; r < 4; ++r) {
        union { float f; u32 u; } cv; cv.f = acc[i][j][r] + bv;
        __hip_atomic_store((u32*)Cout + (size_t)(m + r) * G3_N + n, cv.u,
                           __ATOMIC_RELAXED, __HIP_MEMORY_SCOPE_AGENT);
      }
    }
  }
}

__device__ void seq_body(const void* __restrict__ Whh, const void* __restrict__ bhh,
                         const float* __restrict__ gi, float* __restrict__ ctx,
                         u32 wm, u32 bm, int dir, int blk, char* smem, int tid,
                         int nsteps) {
  u16* wsh = (u16*)smem;                   // 48*1024 bf16 = 96 KB
  const int dirofs = dir << 10;
  const int wave = tid >> 6, lane = tid & 63;
  const int j0 = blk * COLS;
  const int jw = wave * 4;

  for (int e = tid * 8; e < 48 * 1024; e += 256 * 8) {
    const int lr = e >> 10, col = e & 1023;
    const int g = lr >> 4, jj = lr & 15;
    *(short8*)&wsh[e] = ld8(Whh, (size_t)(g * 1024 + j0 + jj) * 1024 + col, wm);
  }
  float br = 0.f, bz = 0.f, bn = 0.f;
  if (lane < 4) {
    br = ld1(bhh, 0 * 1024 + j0 + jw + lane, bm);
    bz = ld1(bhh, 1 * 1024 + j0 + jw + lane, bm);
    bn = ld1(bhh, 2 * 1024 + j0 + jw + lane, bm);
  }
  __syncthreads();

  float hp = 0.f;
  for (int t = 0; t < nsteps; ++t) {
    const int row = dir ? (nsteps - 1 - t) : t;
    // gi poll (sentinel-published by the co-resident GEMM blocks)
    u32 ga = 0, gb = 0, gc = 0;
    {
      const u32* gp = (const u32*)(gi + (size_t)row * G3_N + (j0 + jw + (lane & 3)));
      for (;;) {
        if (lane < 4) {
          ga = __hip_atomic_load(gp,        __ATOMIC_RELAXED, __HIP_MEMORY_SCOPE_AGENT);
          gb = __hip_atomic_load(gp + 1024, __ATOMIC_RELAXED, __HIP_MEMORY_SCOPE_AGENT);
          gc = __hip_atomic_load(gp + 2048, __ATOMIC_RELAXED, __HIP_MEMORY_SCOPE_AGENT);
        }
        const bool bad = (lane < 4) && (ga == SENT || gb == SENT || gc == SENT);
        if (__ballot(bad) == 0ull) break;
      }
    }
    union { u32 u; float f; } c0, c1, c2;
    c0.u = ga; c1.u = gb; c2.u = gc;
    const float ir = c0.f, iz = c1.f, inn = c2.f;

    float hreg[16];
    if (t == 0) {
#pragma unroll
      for (int i = 0; i < 16; ++i) hreg[i] = 0.f;
    } else {
      const int prow = dir ? (nsteps - t) : (t - 1);
      const u64* hsrc = (const u64*)(ctx + (size_t)prow * 2048 + dirofs);
      u64 hv[8];
      for (;;) {
        bool bad = false;
#pragma unroll
        for (int c = 0; c < 8; ++c) {
          hv[c] = __hip_atomic_load(hsrc + c * 64 + lane,
                                    __ATOMIC_RELAXED, __HIP_MEMORY_SCOPE_AGENT);
          if ((u32)hv[c] == SENT || (u32)(hv[c] >> 32) == SENT)
            bad = true;
        }
        if (__ballot(bad) == 0ull) break;
      }
#pragma unroll
      for (int c = 0; c < 8; ++c) {
        union { u64 u; float f[2]; } cv; cv.u = hv[c];
        hreg[2 * c]     = cv.f[0];
        hreg[2 * c + 1] = cv.f[1];
      }
    }
    float sv[12];
#pragma unroll
    for (int g = 0; g < 3; ++g)
#pragma unroll
      for (int jj = 0; jj < 4; ++jj) {
        const u32* wrow = (const u32*)&wsh[(g * 16 + jw + jj) * 1024];
        float s = 0.f;
#pragma unroll
        for (int c = 0; c < 8; ++c) {
          const u32 u = wrow[c * 64 + lane];
          union { u32 i; float f; } lo2, hi2;
          lo2.i = u << 16; hi2.i = u & 0xffff0000u;
          s = fmaf(lo2.f, hreg[2 * c], s);
          s = fmaf(hi2.f, hreg[2 * c + 1], s);
        }
#pragma unroll
        for (int off = 32; off > 0; off >>= 1) s += __shfl_xor(s, off);
        sv[g * 4 + jj] = s;
      }
    if (lane < 4) {
      const float hr = (lane == 0 ? sv[0] : lane == 1 ? sv[1] : lane == 2 ? sv[2] : sv[3]) + br;
      const float hz = (lane == 0 ? sv[4] : lane == 1 ? sv[5] : lane == 2 ? sv[6] : sv[7]) + bz;
      const float hn = (lane == 0 ? sv[8] : lane == 1 ? sv[9] : lane == 2 ? sv[10] : sv[11]) + bn;
      const float r = 1.f / (1.f + expf(-(ir + hr)));
      const float z = 1.f / (1.f + expf(-(iz + hz)));
      const float n = tanhf(inn + r * hn);
      const float ho = (1.f - z) * n + z * hp;
      hp = ho;
      union { float f; u32 i; } v; v.f = ho;
      __hip_atomic_store((u32*)(ctx + (size_t)row * 2048) + dirofs + j0 + jw + lane,
                         v.i, __ATOMIC_RELAXED, __HIP_MEMORY_SCOPE_AGENT);
    }
  }
}

__global__ __launch_bounds__(256)
void p2_kernel(const void* __restrict__ Whf, const void* __restrict__ bhf,
               const void* __restrict__ Whb, const void* __restrict__ bhb,
               const void* __restrict__ Wif, const void* __restrict__ bif,
               const void* __restrict__ Wib, const void* __restrict__ bib,
               const float* __restrict__ wemb, float* __restrict__ G0,
               float* __restrict__ G1, float* __restrict__ ctx,
               const u32* __restrict__ flags, int nsteps) {
  __shared__ __align__(16) char smem[48 * 1024 * 2];   // 96 KB, carved per role
  const int tid = threadIdx.x;
  const int bid = blockIdx.x;
  if (bid < 2 * NBLK) {
    const int dir = bid >> 6, blk = bid & 63;
    seq_body(dir ? Whb : Whf, dir ? bhb : bhf, dir ? G1 : G0, ctx,
             flags[dir ? 11 : 7], flags[dir ? 13 : 9], dir, blk, smem, tid, nsteps);
  } else {
    int b = bid - 2 * NBLK;
    if (b < 1536) {                        // fwd gi: row tiles ascending
      const int bx = b % 48, by = b / 48;
      mgemm_body(wemb, Wif, bif, G0, flags[6], flags[8], by * 64, bx * 64, smem, tid);
    } else {                               // bwd gi: row tiles descending
      b -= 1536;
      const int bx = b % 48, by = 31 - (b / 48);
      mgemm_body(wemb, Wib, bib, G1, flags[10], flags[12], by * 64, bx * 64, smem, tid);
    }
  }
}

// Single-direction segment word-GRU (small-ws fallback, unchanged).
__global__ __launch_bounds__(256)
void seq_kernel(const void* __restrict__ Whh, const void* __restrict__ bhh,
                const float* __restrict__ gi, float* hb, unsigned* cnt,
                float* __restrict__ ctx, const u32* __restrict__ flags,
                int wfi, int bfi, int word_base, int rev, int dirofs) {
  const u32 wm = flags[wfi], bm = flags[bfi];
  const int blk = blockIdx.x;
  const int tid = threadIdx.x;
  const int wave = tid >> 6, lane = tid & 63;
  const int j0 = blk * 8;

  __shared__ __align__(16) u16 wsh[24 * 1024];
  __shared__ float hshf[1024];
  __shared__ float ghs[24];
  __shared__ float bhs[24];
  __shared__ float hnew[8];

  for (int e = tid * 8; e < 24 * 1024; e += 256 * 8) {
    const int lr = e >> 10, col = e & 1023;
    const int g = lr >> 3, jj = lr & 7;
    *(short8*)&wsh[e] = ld8(Whh, (size_t)(g * 1024 + j0 + jj) * 1024 + col, wm);
  }
  if (tid < 24) bhs[tid] = ld1(bhh, (tid >> 3) * 1024 + j0 + (tid & 7), bm);
  __syncthreads();

  unsigned target = 0;
  for (int t = 0; t < SEG; ++t) {
    const int row = rev ? (SEG - 1 - t) : t;
    const int wt = word_base + row;
    const u32* hsrc = (const u32*)(hb + (t & 1) * 1024);
    u32* hdst = (u32*)hshf;
    if (wave == 0) {
#pragma unroll
      for (int c = 0; c < 16; ++c)
        hdst[c * 64 + lane] = __hip_atomic_load(hsrc + c * 64 + lane,
                                                __ATOMIC_RELAXED, __HIP_MEMORY_SCOPE_AGENT);
    }
    __syncthreads();
    float hreg[16];
#pragma unroll
    for (int c = 0; c < 8; ++c) {
      const int kp = 2 * (c * 64 + lane);
      hreg[2 * c]     = hshf[kp];
      hreg[2 * c + 1] = hshf[kp + 1];
    }
#pragma unroll
    for (int q = 0; q < 6; ++q) {
      const int lr = wave * 6 + q;
      const u32* wrow = (const u32*)&wsh[lr * 1024];
      float s = 0.f;
#pragma unroll
      for (int c = 0; c < 8; ++c) {
        const u32 u = wrow[c * 64 + lane];
        union { u32 i; float f; } lo, hi;
        lo.i = u << 16; hi.i = u & 0xffff0000u;
        s = fmaf(lo.f, hreg[2 * c], s);
        s = fmaf(hi.f, hreg[2 * c + 1], s);
      }
#pragma unroll
      for (int off = 32; off > 0; off >>= 1) s += __shfl_xor(s, off);
      if (lane == 0) ghs[lr] = s;
    }
    __syncthreads();
    if (tid < 8) {
      const int jj = tid;
      const float hr = ghs[jj] + bhs[jj];
      const float hz = ghs[8 + jj] + bhs[8 + jj];
      const float hn = ghs[16 + jj] + bhs[16 + jj];
      const float* gim = gi + (size_t)row * G3_N + (j0 + jj);
      const float ir = gim[0], iz = gim[1024], inn = gim[2048];
      const float r = 1.f / (1.f + expf(-(ir + hr)));
      const float z = 1.f / (1.f + expf(-(iz + hz)));
      const float n = tanhf(inn + r * hn);
      const float hp = hshf[j0 + jj];
      const float ho = (1.f - z) * n + z * hp;
      ctx[(size_t)wt * 2048 + dirofs + j0 + jj] = ho;
      hnew[jj] = ho;
    }
    __syncthreads();
    if (tid < 8) {
      union { float f; u32 i; } v; v.f = hnew[tid];
      __hip_atomic_store((u32*)(hb + ((t + 1) & 1) * 1024) + blk * 8 + tid, v.i,
                         __ATOMIC_RELAXED, __HIP_MEMORY_SCOPE_AGENT);
    }
    target += 128;
    if (tid == 0) {
      __hip_atomic_fetch_add(cnt, 1u, __ATOMIC_RELEASE, __HIP_MEMORY_SCOPE_AGENT);
      while (__hip_atomic_load(cnt, __ATOMIC_ACQUIRE, __HIP_MEMORY_SCOPE_AGENT) < target)
        __builtin_amdgcn_s_sleep(2);
    }
    __syncthreads();
  }
}

extern "C" void kernel_launch(void* const* d_in, const int* in_sizes, int n_in,
                              void* d_out, int out_size, void* d_ws, size_t ws_size,
                              hipStream_t stream) {
  char* w = (char*)d_ws;
  // control block: flags [0,64) | cnts [64,1024) | hbuf fp32 [1024,17408)
  u32* flags = (u32*)(w);
  float* hbuf = (float*)(w + 1024);
  const size_t GBASE = 20480;

  hipMemsetAsync(w, 0, GBASE, stream);

  PtrPack pk;
  for (int i = 0; i < 14; ++i) pk.p[i] = d_in[i];
  sniffall_kernel<<<14, 64, 0, stream>>>(pk, flags);

  float* wemb = (float*)d_out;
  float* ctx  = (float*)d_out + (size_t)W_N * H_N;

  const size_t SZ_P  = (size_t)128 * G3_N * 4;         // 1.57 MB (P, 128 rows)
  const size_t SZ_G  = (size_t)W_N * G3_N * 4;         // 25.2 MB
  const size_t SZ_HF = (size_t)W_N * H_N * 4;          // 8.4 MB
  const size_t needA = GBASE + SZ_P + 2 * SZ_G + SZ_HF;

  if (ws_size >= needA) {
    // ---------- big-workspace path ----------
    float* P  = (float*)(w + GBASE);                   // emb @ Wih1^T + bih1
    float* G0 = (float*)(w + GBASE + SZ_P);            // gi fwd (phase 2)
    float* G1 = G0 + (size_t)W_N * G3_N;               // gi bwd (phase 2)
    float* HA = G1 + (size_t)W_N * G3_N;               // h fp32 double-buffer A
    float* HB = G0;                                    // h fp32 double-buffer B (G0 head)
    // phase-1 scratch overlaid in G0/G1 (both free until phase 2):
    u16* Whi  = (u16*)((char*)G0 + SZ_HF);             // pre-split Whh1 hi (6.3 MB)
    u16* Wlo  = Whi + (size_t)G3_N * H_N;              // pre-split Whh1 lo (6.3 MB)
    u16* pAhi = (u16*)G1;                              // h pair A hi (4.2 MB)
    u16* pAlo = pAhi + (size_t)W_N * H_N;              // h pair A lo
    u16* pBhi = pAlo + (size_t)W_N * H_N;              // h pair B hi
    u16* pBlo = pBhi + (size_t)W_N * H_N;              // h pair B lo

    hipMemsetAsync(HA, 0, SZ_HF, stream);              // h0 fp32 = 0
    hipMemsetAsync(pAhi, 0, (size_t)W_N * H_N * 4, stream);  // h0 pair = 0 (hi+lo)

    // prep: P[v] = emb[v] @ Wih1^T + bih1 (3-pass fp32) ; Whh1 -> hi/lo planes
    mgemm_kernel<2><<<dim3(G3_N / 64, 2), 256, 0, stream>>>(
        d_in[1], d_in[2], d_in[4], P, nullptr, 0, 0, E_N, flags, 1, 2, 4, 0);
    wsplit_kernel<<<(G3_N * H_N / 8 + 255) / 256, 256, 0, stream>>>(
        d_in[3], Whi, Wlo, flags, 3, G3_N * H_N / 8);

    // phase 1: 24 fused GRU-cell steps (pair-staged h-GEMM + P-gather + cell)
    float* hF[2]  = {HA, HB};
    u16*   pHi[2] = {pAhi, pBhi};
    u16*   pLo[2] = {pAlo, pBlo};
    dim3 gf(H_N / 64, W_N / 64);                       // 16 x 32
    for (int c = 0; c < C_N; ++c) {
      fgru_kernel<<<gf, 256, 0, stream>>>(P, Whi, Wlo, d_in[5],
                                          hF[c & 1], pHi[c & 1], pLo[c & 1],
                                          hF[(c + 1) & 1], pHi[(c + 1) & 1], pLo[(c + 1) & 1],
                                          (c == C_N - 1) ? wemb : (float*)nullptr,
                                          d_in[0], c, C_N, flags);
    }

    // sentinel prefill (G0/G1 were phase-1 scratch, so prefill AFTER phase 1)
    hipMemsetAsync(G0, 0xFF, SZ_G, stream);
    hipMemsetAsync(G1, 0xFF, SZ_G, stream);
    hipMemsetAsync(ctx, 0xFF, (size_t)W_N * 2048 * 4, stream);

    // phase 2 mega-kernel: seq chains + both gi GEMMs co-resident
    p2_kernel<<<2 * NBLK + 2 * 1536, 256, 0, stream>>>(
        d_in[7], d_in[9], d_in[11], d_in[13],
        d_in[6], d_in[8], d_in[10], d_in[12],
        wemb, G0, G1, ctx, flags, W_N);
  } else {
    // ---------- small-workspace fallback ----------
    float* G0  = (float*)(w + GBASE);
    float* GIc = G0;
    float* GHc = G0 + (size_t)CH * G3_N;
    float* HF  = (float*)(w + GBASE + (size_t)SEG * G3_N * 4);

    dim3 g1(G3_N / 64, CH / 64);
    for (int chk = 0; chk < W_N / CH; ++chk) {
      const int mb = chk * CH;
      hipMemsetAsync(HF, 0, (size_t)CH * H_N * 4, stream);
      for (int c = 0; c < C_N; ++c) {
        mgemm_kernel<1><<<g1, 256, 0, stream>>>(d_in[1], d_in[2], d_in[4], GIc,
                                                d_in[0], c, C_N, E_N, flags, 1, 2, 4, mb);
        mgemm_kernel<0><<<g1, 256, 0, stream>>>(HF, d_in[3], d_in[5], GHc,
                                                nullptr, 0, 0, H_N, flags, -2, 3, 5, 0);
        gru_cell_kernel<<<(CH * H_N) / 256, 256, 0, stream>>>(
            GIc, GHc, HF, (c == C_N - 1) ? wemb : (float*)nullptr, mb);
      }
    }
    dim3 g2(G3_N / 64, SEG / 64);
    for (int s = 0; s < W_N / SEG; ++s) {
      mgemm_kernel<0><<<g2, 256, 0, stream>>>(wemb, d_in[6], d_in[8], G0,
                                              nullptr, 0, 0, H_N, flags, -2, 6, 8, s * SEG);
      seq_kernel<<<128, 256, 0, stream>>>(d_in[7], d_in[9], G0, hbuf,
                                          (unsigned*)(w + 64 + (0 * 4 + s) * 64),
                                          ctx, flags, 7, 9, s * SEG, 0, 0);
    }
    for (int s = W_N / SEG - 1; s >= 0; --s) {
      mgemm_kernel<0><<<g2, 256, 0, stream>>>(wemb, d_in[10], d_in[12], G0,
                                              nullptr, 0, 0, H_N, flags, -2, 10, 12, s * SEG);
      seq_kernel<<<128, 256, 0, stream>>>(d_in[11], d_in[13], G0, hbuf + 2048,
                                          (unsigned*)(w + 64 + (1 * 4 + s) * 64),
                                          ctx, flags, 11, 13, s * SEG, 1, 1024);
    }
  }
}